// Round 1
// baseline (596.654 us; speedup 1.0000x reference)
//
#include <hip/hip_runtime.h>

#define NN 10000
#define PP 32
#define QQ 64
#define BB 32
#define EE 160000
#define MM 5
#define FF 1024           // P*B
#define F4V 256           // FF/4

// ---------------- transpose: inputs [B, N*P] -> x0 [N, F], f = p*B + b ----------------
__global__ __launch_bounds__(256)
void transpose_kernel(const float* __restrict__ in, float* __restrict__ x0) {
    __shared__ float lds[PP][BB + 1];
    int n = blockIdx.x;
    int t = threadIdx.x;
#pragma unroll
    for (int j = 0; j < 4; ++j) {
        int idx = t + j * 256;      // 0..1023
        int b = idx >> 5;
        int p = idx & 31;
        lds[p][b] = in[(size_t)b * (NN * PP) + (size_t)n * PP + p];
    }
    __syncthreads();
#pragma unroll
    for (int j = 0; j < 4; ++j) {
        int f = t + j * 256;
        int p = f >> 5;
        int b = f & 31;
        x0[(size_t)n * FF + f] = lds[p][b];
    }
}

// ---------------- CSR build ----------------
__global__ __launch_bounds__(256)
void zero_kernel(int* __restrict__ p, int n) {
    int i = blockIdx.x * 256 + threadIdx.x;
    if (i < n) p[i] = 0;
}

__global__ __launch_bounds__(256)
void hist_kernel(const int* __restrict__ rows, int* __restrict__ counts) {
    int e = blockIdx.x * 256 + threadIdx.x;
    if (e < EE) atomicAdd(&counts[rows[e]], 1);
}

__global__ __launch_bounds__(1024)
void scan_kernel(const int* __restrict__ counts, int* __restrict__ row_ptr, int* __restrict__ wo) {
    __shared__ int lds[1024];
    __shared__ int carry_s;
    int t = threadIdx.x;
    if (t == 0) { carry_s = 0; row_ptr[0] = 0; }
    __syncthreads();
    for (int base = 0; base < NN; base += 1024) {
        int i = base + t;
        int v = (i < NN) ? counts[i] : 0;
        lds[t] = v;
        __syncthreads();
        for (int off = 1; off < 1024; off <<= 1) {
            int add = (t >= off) ? lds[t - off] : 0;
            __syncthreads();
            lds[t] += add;
            __syncthreads();
        }
        int carry = carry_s;
        if (i < NN) {
            int incl = carry + lds[t];
            row_ptr[i + 1] = incl;
            wo[i] = incl - v;           // exclusive prefix = scatter base
        }
        __syncthreads();
        if (t == 1023) carry_s = carry + lds[1023];
        __syncthreads();
    }
}

__global__ __launch_bounds__(256)
void scatter_kernel(const int* __restrict__ rows, const int* __restrict__ cols,
                    const float* __restrict__ vals, int* __restrict__ wo,
                    int* __restrict__ csr_col, float* __restrict__ csr_val) {
    int e = blockIdx.x * 256 + threadIdx.x;
    if (e < EE) {
        int r = rows[e];
        int pos = atomicAdd(&wo[r], 1);
        csr_col[pos] = cols[e];
        csr_val[pos] = vals[e];
    }
}

// ---------------- SpMM (CSR, row-per-block, dual graphs in one launch) ----------------
// out = alpha * (A @ x) - (sub ? sub : 0)
__global__ __launch_bounds__(256)
void spmm_dual_kernel(const int* __restrict__ rpA, const int* __restrict__ colA, const float* __restrict__ cvA,
                      const float* __restrict__ xA, float* __restrict__ outA,
                      const int* __restrict__ rpB, const int* __restrict__ colB, const float* __restrict__ cvB,
                      const float* __restrict__ xB, float* __restrict__ outB,
                      const float* __restrict__ sub, float alpha) {
    int bid = blockIdx.x;
    const int* rp; const int* col; const float* cv; const float* x; float* out;
    int n;
    if (bid < NN) { n = bid;      rp = rpA; col = colA; cv = cvA; x = xA; out = outA; }
    else          { n = bid - NN; rp = rpB; col = colB; cv = cvB; x = xB; out = outB; }
    int t = threadIdx.x;
    int e = rp[n], eend = rp[n + 1];
    const float4* xv = (const float4*)x;
    float4 acc = make_float4(0.f, 0.f, 0.f, 0.f);
    for (; e + 1 < eend; e += 2) {
        int c0 = col[e];     int c1 = col[e + 1];
        float v0 = cv[e];    float v1 = cv[e + 1];
        float4 a = xv[(size_t)c0 * F4V + t];
        float4 b = xv[(size_t)c1 * F4V + t];
        acc.x += v0 * a.x + v1 * b.x;
        acc.y += v0 * a.y + v1 * b.y;
        acc.z += v0 * a.z + v1 * b.z;
        acc.w += v0 * a.w + v1 * b.w;
    }
    if (e < eend) {
        int c0 = col[e]; float v0 = cv[e];
        float4 a = xv[(size_t)c0 * F4V + t];
        acc.x += v0 * a.x; acc.y += v0 * a.y; acc.z += v0 * a.z; acc.w += v0 * a.w;
    }
    float4 o;
    if (sub) {
        float4 s4 = ((const float4*)sub)[(size_t)n * F4V + t];
        o.x = alpha * acc.x - s4.x;
        o.y = alpha * acc.y - s4.y;
        o.z = alpha * acc.z - s4.z;
        o.w = alpha * acc.w - s4.w;
    } else {
        o = acc;
    }
    ((float4*)out)[(size_t)n * F4V + t] = o;
}

// ---------------- final GEMM: out[b, n*Q+q] = bias[q] + sum_{p,m} xs[m][n, p*B+b] * W[p*M+m, q] ----------------
__global__ __launch_bounds__(256)
void gemm_kernel(const float* __restrict__ xs, const float* __restrict__ W,
                 const float* __restrict__ bias, float* __restrict__ out) {
    __shared__ __align__(16) float wlds[160 * 64];       // 40 KB
    __shared__ __align__(16) float xlds[2 * 5 * 1024];   // 40 KB (2 nodes x 5 mats x 1024)
    int t = threadIdx.x;
    int n0 = blockIdx.x * 2;

    const float4* w4 = (const float4*)W;
    float4* wl4 = (float4*)wlds;
#pragma unroll
    for (int j = 0; j < 10; ++j) wl4[t + j * 256] = w4[t + j * 256];

    const float4* xsv = (const float4*)xs;
    float4* xl4 = (float4*)xlds;
#pragma unroll
    for (int j = 0; j < 10; ++j) {
        int idx = t + j * 256;          // 0..2559
        int node = idx / 1280;
        int rem = idx - node * 1280;
        int m = rem >> 8;
        int f4 = rem & 255;
        xl4[idx] = xsv[(size_t)m * (NN * F4V) + (size_t)(n0 + node) * F4V + f4];
    }
    __syncthreads();

    int b  = t >> 3;            // 0..31
    int qb = (t & 7) * 8;       // 0,8,...,56
    float acc0[8], acc1[8];
#pragma unroll
    for (int j = 0; j < 8; ++j) { acc0[j] = 0.f; acc1[j] = 0.f; }

    const float* xA = xlds;
    const float* xB = xlds + 5 * 1024;
    for (int p = 0; p < 32; ++p) {
#pragma unroll
        for (int m = 0; m < 5; ++m) {
            float s0 = xA[m * 1024 + p * 32 + b];
            float s1 = xB[m * 1024 + p * 32 + b];
            int k = p * 5 + m;
            float4 wA = *(const float4*)&wlds[k * 64 + qb];
            float4 wB = *(const float4*)&wlds[k * 64 + qb + 4];
            acc0[0] += s0 * wA.x; acc0[1] += s0 * wA.y; acc0[2] += s0 * wA.z; acc0[3] += s0 * wA.w;
            acc0[4] += s0 * wB.x; acc0[5] += s0 * wB.y; acc0[6] += s0 * wB.z; acc0[7] += s0 * wB.w;
            acc1[0] += s1 * wA.x; acc1[1] += s1 * wA.y; acc1[2] += s1 * wA.z; acc1[3] += s1 * wA.w;
            acc1[4] += s1 * wB.x; acc1[5] += s1 * wB.y; acc1[6] += s1 * wB.z; acc1[7] += s1 * wB.w;
        }
    }

    float4 bA = *(const float4*)&bias[qb];
    float4 bB = *(const float4*)&bias[qb + 4];
    {
        size_t o = (size_t)b * ((size_t)NN * QQ) + (size_t)n0 * QQ + qb;
        float4 r0 = make_float4(acc0[0] + bA.x, acc0[1] + bA.y, acc0[2] + bA.z, acc0[3] + bA.w);
        float4 r1 = make_float4(acc0[4] + bB.x, acc0[5] + bB.y, acc0[6] + bB.z, acc0[7] + bB.w);
        *(float4*)&out[o]     = r0;
        *(float4*)&out[o + 4] = r1;
    }
    {
        size_t o = (size_t)b * ((size_t)NN * QQ) + (size_t)(n0 + 1) * QQ + qb;
        float4 r0 = make_float4(acc1[0] + bA.x, acc1[1] + bA.y, acc1[2] + bA.z, acc1[3] + bA.w);
        float4 r1 = make_float4(acc1[4] + bB.x, acc1[5] + bB.y, acc1[6] + bB.z, acc1[7] + bB.w);
        *(float4*)&out[o]     = r0;
        *(float4*)&out[o + 4] = r1;
    }
}

extern "C" void kernel_launch(void* const* d_in, const int* in_sizes, int n_in,
                              void* d_out, int out_size, void* d_ws, size_t ws_size,
                              hipStream_t stream) {
    const float* inputs = (const float*)d_in[0];
    const int*   t1i    = (const int*)d_in[1];
    const float* t1v    = (const float*)d_in[2];
    const int*   t2i    = (const int*)d_in[3];
    const float* t2v    = (const float*)d_in[4];
    const float* W      = (const float*)d_in[5];
    const float* bias   = (const float*)d_in[6];
    float* out = (float*)d_out;

    float* ws = (float*)d_ws;
    const size_t NF = (size_t)NN * FF;
    float* x0  = ws;                 // m = 0
    float* xs1 = ws + 1 * NF;        // m = 1 (t1, x1)
    float* xs2 = ws + 2 * NF;        // m = 2 (t1, x2)
    float* xs3 = ws + 3 * NF;        // m = 3 (t2, x1)
    float* xs4 = ws + 4 * NF;        // m = 4 (t2, x2)
    int* rp1  = (int*)(ws + 5 * NF); // N+1
    int* rp2  = rp1 + (NN + 1);
    int* wo1  = rp2 + (NN + 1);
    int* wo2  = wo1 + NN;
    int* cnt1 = wo2 + NN;            // cnt1 + cnt2 contiguous (2N)
    int* cnt2 = cnt1 + NN;
    int* col1 = cnt2 + NN;
    int* col2 = col1 + EE;
    float* cv1 = (float*)(col2 + EE);
    float* cv2 = cv1 + EE;

    const int* r1 = t1i;        // idx[0]
    const int* c1 = t1i + EE;   // idx[1]
    const int* r2 = t2i;
    const int* c2 = t2i + EE;

    zero_kernel<<<(2 * NN + 255) / 256, 256, 0, stream>>>(cnt1, 2 * NN);
    transpose_kernel<<<NN, 256, 0, stream>>>(inputs, x0);
    hist_kernel<<<(EE + 255) / 256, 256, 0, stream>>>(r1, cnt1);
    hist_kernel<<<(EE + 255) / 256, 256, 0, stream>>>(r2, cnt2);
    scan_kernel<<<1, 1024, 0, stream>>>(cnt1, rp1, wo1);
    scan_kernel<<<1, 1024, 0, stream>>>(cnt2, rp2, wo2);
    scatter_kernel<<<(EE + 255) / 256, 256, 0, stream>>>(r1, c1, t1v, wo1, col1, cv1);
    scatter_kernel<<<(EE + 255) / 256, 256, 0, stream>>>(r2, c2, t2v, wo2, col2, cv2);

    // step 1: x1 = A @ x0 (both transitions in one launch)
    spmm_dual_kernel<<<2 * NN, 256, 0, stream>>>(rp1, col1, cv1, x0, xs1,
                                                 rp2, col2, cv2, x0, xs3,
                                                 nullptr, 1.0f);
    // step 2: x2 = 2 * (A @ x1) - x0 (fused Chebyshev epilogue)
    spmm_dual_kernel<<<2 * NN, 256, 0, stream>>>(rp1, col1, cv1, xs1, xs2,
                                                 rp2, col2, cv2, xs3, xs4,
                                                 x0, 2.0f);

    gemm_kernel<<<NN / 2, 256, 0, stream>>>(ws, W, bias, out);
}

// Round 2
// 574.516 us; speedup vs baseline: 1.0385x; 1.0385x over previous
//
#include <hip/hip_runtime.h>

#define NN 10000
#define PP 32
#define QQ 64
#define BB 32
#define EE 160000
#define MM 5
#define FF 1024           // P*B
#define F4V 256           // FF/4
#define WCH 64            // floats per feature chunk
#define NCH 16            // number of chunks (2 phases x 8 XCDs)

// ---------------- transpose: inputs [B, N*P] -> x0 [N, F], f = p*B + b ----------------
__global__ __launch_bounds__(256)
void transpose_kernel(const float* __restrict__ in, float* __restrict__ x0) {
    __shared__ float lds[PP][BB + 1];
    int n = blockIdx.x;
    int t = threadIdx.x;
#pragma unroll
    for (int j = 0; j < 4; ++j) {
        int idx = t + j * 256;      // 0..1023
        int b = idx >> 5;
        int p = idx & 31;
        lds[p][b] = in[(size_t)b * (NN * PP) + (size_t)n * PP + p];
    }
    __syncthreads();
#pragma unroll
    for (int j = 0; j < 4; ++j) {
        int f = t + j * 256;
        int p = f >> 5;
        int b = f & 31;
        x0[(size_t)n * FF + f] = lds[p][b];
    }
}

// ---------------- CSR build ----------------
__global__ __launch_bounds__(256)
void zero_kernel(int* __restrict__ p, int n) {
    int i = blockIdx.x * 256 + threadIdx.x;
    if (i < n) p[i] = 0;
}

__global__ __launch_bounds__(256)
void hist_kernel(const int* __restrict__ rows, int* __restrict__ counts) {
    int e = blockIdx.x * 256 + threadIdx.x;
    if (e < EE) atomicAdd(&counts[rows[e]], 1);
}

__global__ __launch_bounds__(1024)
void scan_kernel(const int* __restrict__ counts, int* __restrict__ row_ptr, int* __restrict__ wo) {
    __shared__ int lds[1024];
    __shared__ int carry_s;
    int t = threadIdx.x;
    if (t == 0) { carry_s = 0; row_ptr[0] = 0; }
    __syncthreads();
    for (int base = 0; base < NN; base += 1024) {
        int i = base + t;
        int v = (i < NN) ? counts[i] : 0;
        lds[t] = v;
        __syncthreads();
        for (int off = 1; off < 1024; off <<= 1) {
            int add = (t >= off) ? lds[t - off] : 0;
            __syncthreads();
            lds[t] += add;
            __syncthreads();
        }
        int carry = carry_s;
        if (i < NN) {
            int incl = carry + lds[t];
            row_ptr[i + 1] = incl;
            wo[i] = incl - v;           // exclusive prefix = scatter base
        }
        __syncthreads();
        if (t == 1023) carry_s = carry + lds[1023];
        __syncthreads();
    }
}

__global__ __launch_bounds__(256)
void scatter_kernel(const int* __restrict__ rows, const int* __restrict__ cols,
                    const float* __restrict__ vals, int* __restrict__ wo,
                    int* __restrict__ csr_col, float* __restrict__ csr_val) {
    int e = blockIdx.x * 256 + threadIdx.x;
    if (e < EE) {
        int r = rows[e];
        int pos = atomicAdd(&wo[r], 1);
        csr_col[pos] = cols[e];
        csr_val[pos] = vals[e];
    }
}

// ---------------- SpMM, feature-chunked + XCD-affine ----------------
// Grid: bid = ((seg * 2500) + r4) * 8 + c, seg = g*2 + phase, 4 segs -> 80000 blocks.
// XCD = bid % 8 = c (round-robin dispatch); chunk = phase*8 + c, so each XCD's
// live working set is one 2.5 MB column-slice of x -> fits its 4 MiB L2.
// One wave per (row, chunk): lane reads x[col][chunk*64 + lane].
// out = alpha * (A @ x) - (sub ? sub : 0)
__global__ __launch_bounds__(256)
void spmm_chunked_kernel(const int* __restrict__ rp1, const int* __restrict__ col1, const float* __restrict__ cv1,
                         const int* __restrict__ rp2, const int* __restrict__ col2, const float* __restrict__ cv2,
                         const float* __restrict__ x1src, const float* __restrict__ x2src,
                         float* __restrict__ out1, float* __restrict__ out2,
                         const float* __restrict__ sub, float alpha) {
    int bid = blockIdx.x;
    int c = bid & 7;
    int rest = bid >> 3;
    int r4 = rest % 2500;
    int seg = rest / 2500;          // 0..3
    int g = seg >> 1;
    int phase = seg & 1;
    int fbase = (phase * 8 + c) * WCH;
    int wid = threadIdx.x >> 6;
    int lane = threadIdx.x & 63;
    int n = r4 * 4 + wid;

    const int* rp; const int* col; const float* cv; const float* x; float* out;
    if (g == 0) { rp = rp1; col = col1; cv = cv1; x = x1src; out = out1; }
    else        { rp = rp2; col = col2; cv = cv2; x = x2src; out = out2; }

    int e = rp[n], eend = rp[n + 1];
    int f = fbase + lane;
    float a0 = 0.f, a1 = 0.f, a2 = 0.f, a3 = 0.f;
    for (; e + 3 < eend; e += 4) {
        int   c0 = col[e],     c1 = col[e + 1], c2 = col[e + 2], c3 = col[e + 3];
        float v0 = cv[e],      v1 = cv[e + 1],  v2 = cv[e + 2],  v3 = cv[e + 3];
        a0 += v0 * x[(size_t)c0 * FF + f];
        a1 += v1 * x[(size_t)c1 * FF + f];
        a2 += v2 * x[(size_t)c2 * FF + f];
        a3 += v3 * x[(size_t)c3 * FF + f];
    }
    for (; e < eend; ++e)
        a0 += cv[e] * x[(size_t)col[e] * FF + f];
    float acc = (a0 + a1) + (a2 + a3);

    float o;
    if (sub) o = alpha * acc - sub[(size_t)n * FF + f];
    else     o = acc;
    out[(size_t)n * FF + f] = o;
}

// ---------------- final GEMM: out[b, n*Q+q] = bias[q] + sum_{p,m} xs[m][n, p*B+b] * W[p*M+m, q] ----------------
__global__ __launch_bounds__(256)
void gemm_kernel(const float* __restrict__ xs, const float* __restrict__ W,
                 const float* __restrict__ bias, float* __restrict__ out) {
    __shared__ __align__(16) float wlds[160 * 64];       // 40 KB
    __shared__ __align__(16) float xlds[2 * 5 * 1024];   // 40 KB (2 nodes x 5 mats x 1024)
    int t = threadIdx.x;
    int n0 = blockIdx.x * 2;

    const float4* w4 = (const float4*)W;
    float4* wl4 = (float4*)wlds;
#pragma unroll
    for (int j = 0; j < 10; ++j) wl4[t + j * 256] = w4[t + j * 256];

    const float4* xsv = (const float4*)xs;
    float4* xl4 = (float4*)xlds;
#pragma unroll
    for (int j = 0; j < 10; ++j) {
        int idx = t + j * 256;          // 0..2559
        int node = idx / 1280;
        int rem = idx - node * 1280;
        int m = rem >> 8;
        int f4 = rem & 255;
        xl4[idx] = xsv[(size_t)m * (NN * F4V) + (size_t)(n0 + node) * F4V + f4];
    }
    __syncthreads();

    int b  = t >> 3;            // 0..31
    int qb = (t & 7) * 8;       // 0,8,...,56
    float acc0[8], acc1[8];
#pragma unroll
    for (int j = 0; j < 8; ++j) { acc0[j] = 0.f; acc1[j] = 0.f; }

    const float* xA = xlds;
    const float* xB = xlds + 5 * 1024;
    for (int p = 0; p < 32; ++p) {
#pragma unroll
        for (int m = 0; m < 5; ++m) {
            float s0 = xA[m * 1024 + p * 32 + b];
            float s1 = xB[m * 1024 + p * 32 + b];
            int k = p * 5 + m;
            float4 wA = *(const float4*)&wlds[k * 64 + qb];
            float4 wB = *(const float4*)&wlds[k * 64 + qb + 4];
            acc0[0] += s0 * wA.x; acc0[1] += s0 * wA.y; acc0[2] += s0 * wA.z; acc0[3] += s0 * wA.w;
            acc0[4] += s0 * wB.x; acc0[5] += s0 * wB.y; acc0[6] += s0 * wB.z; acc0[7] += s0 * wB.w;
            acc1[0] += s1 * wA.x; acc1[1] += s1 * wA.y; acc1[2] += s1 * wA.z; acc1[3] += s1 * wA.w;
            acc1[4] += s1 * wB.x; acc1[5] += s1 * wB.y; acc1[6] += s1 * wB.z; acc1[7] += s1 * wB.w;
        }
    }

    float4 bA = *(const float4*)&bias[qb];
    float4 bB = *(const float4*)&bias[qb + 4];
    {
        size_t o = (size_t)b * ((size_t)NN * QQ) + (size_t)n0 * QQ + qb;
        float4 r0 = make_float4(acc0[0] + bA.x, acc0[1] + bA.y, acc0[2] + bA.z, acc0[3] + bA.w);
        float4 r1 = make_float4(acc0[4] + bB.x, acc0[5] + bB.y, acc0[6] + bB.z, acc0[7] + bB.w);
        *(float4*)&out[o]     = r0;
        *(float4*)&out[o + 4] = r1;
    }
    {
        size_t o = (size_t)b * ((size_t)NN * QQ) + (size_t)(n0 + 1) * QQ + qb;
        float4 r0 = make_float4(acc1[0] + bA.x, acc1[1] + bA.y, acc1[2] + bA.z, acc1[3] + bA.w);
        float4 r1 = make_float4(acc1[4] + bB.x, acc1[5] + bB.y, acc1[6] + bB.z, acc1[7] + bB.w);
        *(float4*)&out[o]     = r0;
        *(float4*)&out[o + 4] = r1;
    }
}

extern "C" void kernel_launch(void* const* d_in, const int* in_sizes, int n_in,
                              void* d_out, int out_size, void* d_ws, size_t ws_size,
                              hipStream_t stream) {
    const float* inputs = (const float*)d_in[0];
    const int*   t1i    = (const int*)d_in[1];
    const float* t1v    = (const float*)d_in[2];
    const int*   t2i    = (const int*)d_in[3];
    const float* t2v    = (const float*)d_in[4];
    const float* W      = (const float*)d_in[5];
    const float* bias   = (const float*)d_in[6];
    float* out = (float*)d_out;

    float* ws = (float*)d_ws;
    const size_t NF = (size_t)NN * FF;
    float* x0  = ws;                 // m = 0
    float* xs1 = ws + 1 * NF;        // m = 1 (t1, x1)
    float* xs2 = ws + 2 * NF;        // m = 2 (t1, x2)
    float* xs3 = ws + 3 * NF;        // m = 3 (t2, x1)
    float* xs4 = ws + 4 * NF;        // m = 4 (t2, x2)
    int* rp1  = (int*)(ws + 5 * NF); // N+1
    int* rp2  = rp1 + (NN + 1);
    int* wo1  = rp2 + (NN + 1);
    int* wo2  = wo1 + NN;
    int* cnt1 = wo2 + NN;            // cnt1 + cnt2 contiguous (2N)
    int* cnt2 = cnt1 + NN;
    int* col1 = cnt2 + NN;
    int* col2 = col1 + EE;
    float* cv1 = (float*)(col2 + EE);
    float* cv2 = cv1 + EE;

    const int* r1 = t1i;        // idx[0]
    const int* c1 = t1i + EE;   // idx[1]
    const int* r2 = t2i;
    const int* c2 = t2i + EE;

    zero_kernel<<<(2 * NN + 255) / 256, 256, 0, stream>>>(cnt1, 2 * NN);
    transpose_kernel<<<NN, 256, 0, stream>>>(inputs, x0);
    hist_kernel<<<(EE + 255) / 256, 256, 0, stream>>>(r1, cnt1);
    hist_kernel<<<(EE + 255) / 256, 256, 0, stream>>>(r2, cnt2);
    scan_kernel<<<1, 1024, 0, stream>>>(cnt1, rp1, wo1);
    scan_kernel<<<1, 1024, 0, stream>>>(cnt2, rp2, wo2);
    scatter_kernel<<<(EE + 255) / 256, 256, 0, stream>>>(r1, c1, t1v, wo1, col1, cv1);
    scatter_kernel<<<(EE + 255) / 256, 256, 0, stream>>>(r2, c2, t2v, wo2, col2, cv2);

    const int spmm_grid = 4 * 2500 * 8;   // (2 graphs x 2 phases) x 2500 row-quads x 8 XCD chunks

    // step 1: x1 = A @ x0 (both transitions in one launch, XCD-affine chunks)
    spmm_chunked_kernel<<<spmm_grid, 256, 0, stream>>>(rp1, col1, cv1,
                                                       rp2, col2, cv2,
                                                       x0, x0, xs1, xs3,
                                                       nullptr, 1.0f);
    // step 2: x2 = 2 * (A @ x1) - x0 (fused Chebyshev epilogue)
    spmm_chunked_kernel<<<spmm_grid, 256, 0, stream>>>(rp1, col1, cv1,
                                                       rp2, col2, cv2,
                                                       xs1, xs3, xs2, xs4,
                                                       x0, 2.0f);

    gemm_kernel<<<NN / 2, 256, 0, stream>>>(ws, W, bias, out);
}

// Round 3
// 405.637 us; speedup vs baseline: 1.4709x; 1.4163x over previous
//
#include <hip/hip_runtime.h>

#define NN 10000
#define PP 32
#define QQ 64
#define BB 32
#define EE 160000
#define MM 5
#define FF 1024           // P*B
#define F4V 256           // FF/4
#define WCH 64            // floats per feature chunk
#define NCH 16            // number of chunks (2 phases x 8 XCDs)

// ---------------- transpose: inputs [B, N*P] -> x0 [N, F], f = p*B + b ----------------
__global__ __launch_bounds__(256)
void transpose_kernel(const float* __restrict__ in, float* __restrict__ x0) {
    __shared__ float lds[PP][BB + 1];
    int n = blockIdx.x;
    int t = threadIdx.x;
#pragma unroll
    for (int j = 0; j < 4; ++j) {
        int idx = t + j * 256;      // 0..1023
        int b = idx >> 5;
        int p = idx & 31;
        lds[p][b] = in[(size_t)b * (NN * PP) + (size_t)n * PP + p];
    }
    __syncthreads();
#pragma unroll
    for (int j = 0; j < 4; ++j) {
        int f = t + j * 256;
        int p = f >> 5;
        int b = f & 31;
        x0[(size_t)n * FF + f] = lds[p][b];
    }
}

// ---------------- CSR build ----------------
__global__ __launch_bounds__(256)
void zero_kernel(int* __restrict__ p, int n) {
    int i = blockIdx.x * 256 + threadIdx.x;
    if (i < n) p[i] = 0;
}

__global__ __launch_bounds__(256)
void hist_kernel(const int* __restrict__ rows, int* __restrict__ counts) {
    int e = blockIdx.x * 256 + threadIdx.x;
    if (e < EE) atomicAdd(&counts[rows[e]], 1);
}

__global__ __launch_bounds__(1024)
void scan_kernel(const int* __restrict__ counts, int* __restrict__ row_ptr, int* __restrict__ wo) {
    __shared__ int lds[1024];
    __shared__ int carry_s;
    int t = threadIdx.x;
    if (t == 0) { carry_s = 0; row_ptr[0] = 0; }
    __syncthreads();
    for (int base = 0; base < NN; base += 1024) {
        int i = base + t;
        int v = (i < NN) ? counts[i] : 0;
        lds[t] = v;
        __syncthreads();
        for (int off = 1; off < 1024; off <<= 1) {
            int add = (t >= off) ? lds[t - off] : 0;
            __syncthreads();
            lds[t] += add;
            __syncthreads();
        }
        int carry = carry_s;
        if (i < NN) {
            int incl = carry + lds[t];
            row_ptr[i + 1] = incl;
            wo[i] = incl - v;           // exclusive prefix = scatter base
        }
        __syncthreads();
        if (t == 1023) carry_s = carry + lds[1023];
        __syncthreads();
    }
}

__global__ __launch_bounds__(256)
void scatter_kernel(const int* __restrict__ rows, const int* __restrict__ cols,
                    const float* __restrict__ vals, int* __restrict__ wo,
                    int* __restrict__ csr_col, float* __restrict__ csr_val) {
    int e = blockIdx.x * 256 + threadIdx.x;
    if (e < EE) {
        int r = rows[e];
        int pos = atomicAdd(&wo[r], 1);
        csr_col[pos] = cols[e];
        csr_val[pos] = vals[e];
    }
}

// ---------------- SpMM, feature-chunked + XCD-affine, 16-lane-group float4 ----------------
// Wave = 4 x 16-lane groups; each group owns one row, 16 lanes x float4 = 64-float chunk.
// Grid: bid = ((seg * 625) + rb) * 8 + c, seg = g*2 + phase -> 20000 blocks.
// XCD = bid % 8 = c; chunk = phase*8 + c -> per-XCD live slice = 2.56 MB < 4 MiB L2.
// out = alpha * (A @ x) - (sub ? sub : 0)
__global__ __launch_bounds__(256)
void spmm_chunked_kernel(const int* __restrict__ rp1, const int* __restrict__ col1, const float* __restrict__ cv1,
                         const int* __restrict__ rp2, const int* __restrict__ col2, const float* __restrict__ cv2,
                         const float* __restrict__ x1src, const float* __restrict__ x2src,
                         float* __restrict__ out1, float* __restrict__ out2,
                         const float* __restrict__ sub, float alpha) {
    int bid = blockIdx.x;
    int c = bid & 7;
    int rest = bid >> 3;
    int rb = rest % 625;
    int seg = rest / 625;           // 0..3
    int g = seg >> 1;
    int phase = seg & 1;
    int fbase = (phase * 8 + c) * WCH;
    int wid  = threadIdx.x >> 6;
    int lane = threadIdx.x & 63;
    int grp  = lane >> 4;           // 0..3: which row within the wave
    int l4   = (lane & 15) * 4;     // float4 slot within the 64-float chunk
    int n = rb * 16 + wid * 4 + grp;

    const int* rp; const int* col; const float* cv; const float* x; float* out;
    if (g == 0) { rp = rp1; col = col1; cv = cv1; x = x1src; out = out1; }
    else        { rp = rp2; col = col2; cv = cv2; x = x2src; out = out2; }

    int e = rp[n], eend = rp[n + 1];
    const float* xp = x + fbase + l4;   // per-lane base; per-edge offset is 32-bit col<<10

    float4 A0 = make_float4(0.f, 0.f, 0.f, 0.f);
    float4 A1 = make_float4(0.f, 0.f, 0.f, 0.f);
    float4 A2 = make_float4(0.f, 0.f, 0.f, 0.f);
    float4 A3 = make_float4(0.f, 0.f, 0.f, 0.f);
    for (; e + 3 < eend; e += 4) {
        int   c0 = col[e],  c1 = col[e + 1], c2 = col[e + 2], c3 = col[e + 3];
        float v0 = cv[e],   v1 = cv[e + 1],  v2 = cv[e + 2],  v3 = cv[e + 3];
        float4 xa = *(const float4*)(xp + ((unsigned)c0 << 10));
        float4 xb = *(const float4*)(xp + ((unsigned)c1 << 10));
        float4 xc = *(const float4*)(xp + ((unsigned)c2 << 10));
        float4 xd = *(const float4*)(xp + ((unsigned)c3 << 10));
        A0.x += v0 * xa.x; A0.y += v0 * xa.y; A0.z += v0 * xa.z; A0.w += v0 * xa.w;
        A1.x += v1 * xb.x; A1.y += v1 * xb.y; A1.z += v1 * xb.z; A1.w += v1 * xb.w;
        A2.x += v2 * xc.x; A2.y += v2 * xc.y; A2.z += v2 * xc.z; A2.w += v2 * xc.w;
        A3.x += v3 * xd.x; A3.y += v3 * xd.y; A3.z += v3 * xd.z; A3.w += v3 * xd.w;
    }
    for (; e < eend; ++e) {
        int cc = col[e]; float vv = cv[e];
        float4 xa = *(const float4*)(xp + ((unsigned)cc << 10));
        A0.x += vv * xa.x; A0.y += vv * xa.y; A0.z += vv * xa.z; A0.w += vv * xa.w;
    }
    float4 acc;
    acc.x = (A0.x + A1.x) + (A2.x + A3.x);
    acc.y = (A0.y + A1.y) + (A2.y + A3.y);
    acc.z = (A0.z + A1.z) + (A2.z + A3.z);
    acc.w = (A0.w + A1.w) + (A2.w + A3.w);

    size_t obase = (size_t)n * FF + fbase + l4;
    float4 o;
    if (sub) {
        float4 s4 = *(const float4*)(sub + obase);
        o.x = alpha * acc.x - s4.x;
        o.y = alpha * acc.y - s4.y;
        o.z = alpha * acc.z - s4.z;
        o.w = alpha * acc.w - s4.w;
    } else {
        o = acc;
    }
    *(float4*)(out + obase) = o;
}

// ---------------- final GEMM: out[b, n*Q+q] = bias[q] + sum_{p,m} xs[m][n, p*B+b] * W[p*M+m, q] ----------------
__global__ __launch_bounds__(256)
void gemm_kernel(const float* __restrict__ xs, const float* __restrict__ W,
                 const float* __restrict__ bias, float* __restrict__ out) {
    __shared__ __align__(16) float wlds[160 * 64];       // 40 KB
    __shared__ __align__(16) float xlds[2 * 5 * 1024];   // 40 KB (2 nodes x 5 mats x 1024)
    int t = threadIdx.x;
    int n0 = blockIdx.x * 2;

    const float4* w4 = (const float4*)W;
    float4* wl4 = (float4*)wlds;
#pragma unroll
    for (int j = 0; j < 10; ++j) wl4[t + j * 256] = w4[t + j * 256];

    const float4* xsv = (const float4*)xs;
    float4* xl4 = (float4*)xlds;
#pragma unroll
    for (int j = 0; j < 10; ++j) {
        int idx = t + j * 256;          // 0..2559
        int node = idx / 1280;
        int rem = idx - node * 1280;
        int m = rem >> 8;
        int f4 = rem & 255;
        xl4[idx] = xsv[(size_t)m * (NN * F4V) + (size_t)(n0 + node) * F4V + f4];
    }
    __syncthreads();

    int b  = t >> 3;            // 0..31
    int qb = (t & 7) * 8;       // 0,8,...,56
    float acc0[8], acc1[8];
#pragma unroll
    for (int j = 0; j < 8; ++j) { acc0[j] = 0.f; acc1[j] = 0.f; }

    const float* xA = xlds;
    const float* xB = xlds + 5 * 1024;
    for (int p = 0; p < 32; ++p) {
#pragma unroll
        for (int m = 0; m < 5; ++m) {
            float s0 = xA[m * 1024 + p * 32 + b];
            float s1 = xB[m * 1024 + p * 32 + b];
            int k = p * 5 + m;
            float4 wA = *(const float4*)&wlds[k * 64 + qb];
            float4 wB = *(const float4*)&wlds[k * 64 + qb + 4];
            acc0[0] += s0 * wA.x; acc0[1] += s0 * wA.y; acc0[2] += s0 * wA.z; acc0[3] += s0 * wA.w;
            acc0[4] += s0 * wB.x; acc0[5] += s0 * wB.y; acc0[6] += s0 * wB.z; acc0[7] += s0 * wB.w;
            acc1[0] += s1 * wA.x; acc1[1] += s1 * wA.y; acc1[2] += s1 * wA.z; acc1[3] += s1 * wA.w;
            acc1[4] += s1 * wB.x; acc1[5] += s1 * wB.y; acc1[6] += s1 * wB.z; acc1[7] += s1 * wB.w;
        }
    }

    float4 bA = *(const float4*)&bias[qb];
    float4 bB = *(const float4*)&bias[qb + 4];
    {
        size_t o = (size_t)b * ((size_t)NN * QQ) + (size_t)n0 * QQ + qb;
        float4 r0 = make_float4(acc0[0] + bA.x, acc0[1] + bA.y, acc0[2] + bA.z, acc0[3] + bA.w);
        float4 r1 = make_float4(acc0[4] + bB.x, acc0[5] + bB.y, acc0[6] + bB.z, acc0[7] + bB.w);
        *(float4*)&out[o]     = r0;
        *(float4*)&out[o + 4] = r1;
    }
    {
        size_t o = (size_t)b * ((size_t)NN * QQ) + (size_t)(n0 + 1) * QQ + qb;
        float4 r0 = make_float4(acc1[0] + bA.x, acc1[1] + bA.y, acc1[2] + bA.z, acc1[3] + bA.w);
        float4 r1 = make_float4(acc1[4] + bB.x, acc1[5] + bB.y, acc1[6] + bB.z, acc1[7] + bB.w);
        *(float4*)&out[o]     = r0;
        *(float4*)&out[o + 4] = r1;
    }
}

extern "C" void kernel_launch(void* const* d_in, const int* in_sizes, int n_in,
                              void* d_out, int out_size, void* d_ws, size_t ws_size,
                              hipStream_t stream) {
    const float* inputs = (const float*)d_in[0];
    const int*   t1i    = (const int*)d_in[1];
    const float* t1v    = (const float*)d_in[2];
    const int*   t2i    = (const int*)d_in[3];
    const float* t2v    = (const float*)d_in[4];
    const float* W      = (const float*)d_in[5];
    const float* bias   = (const float*)d_in[6];
    float* out = (float*)d_out;

    float* ws = (float*)d_ws;
    const size_t NF = (size_t)NN * FF;
    float* x0  = ws;                 // m = 0
    float* xs1 = ws + 1 * NF;        // m = 1 (t1, x1)
    float* xs2 = ws + 2 * NF;        // m = 2 (t1, x2)
    float* xs3 = ws + 3 * NF;        // m = 3 (t2, x1)
    float* xs4 = ws + 4 * NF;        // m = 4 (t2, x2)
    int* rp1  = (int*)(ws + 5 * NF); // N+1
    int* rp2  = rp1 + (NN + 1);
    int* wo1  = rp2 + (NN + 1);
    int* wo2  = wo1 + NN;
    int* cnt1 = wo2 + NN;            // cnt1 + cnt2 contiguous (2N)
    int* cnt2 = cnt1 + NN;
    int* col1 = cnt2 + NN;
    int* col2 = col1 + EE;
    float* cv1 = (float*)(col2 + EE);
    float* cv2 = cv1 + EE;

    const int* r1 = t1i;        // idx[0]
    const int* c1 = t1i + EE;   // idx[1]
    const int* r2 = t2i;
    const int* c2 = t2i + EE;

    zero_kernel<<<(2 * NN + 255) / 256, 256, 0, stream>>>(cnt1, 2 * NN);
    transpose_kernel<<<NN, 256, 0, stream>>>(inputs, x0);
    hist_kernel<<<(EE + 255) / 256, 256, 0, stream>>>(r1, cnt1);
    hist_kernel<<<(EE + 255) / 256, 256, 0, stream>>>(r2, cnt2);
    scan_kernel<<<1, 1024, 0, stream>>>(cnt1, rp1, wo1);
    scan_kernel<<<1, 1024, 0, stream>>>(cnt2, rp2, wo2);
    scatter_kernel<<<(EE + 255) / 256, 256, 0, stream>>>(r1, c1, t1v, wo1, col1, cv1);
    scatter_kernel<<<(EE + 255) / 256, 256, 0, stream>>>(r2, c2, t2v, wo2, col2, cv2);

    const int spmm_grid = 4 * 625 * 8;   // (2 graphs x 2 phases) x 625 row-blocks x 8 XCD chunks

    // step 1: x1 = A @ x0 (both transitions in one launch, XCD-affine chunks)
    spmm_chunked_kernel<<<spmm_grid, 256, 0, stream>>>(rp1, col1, cv1,
                                                       rp2, col2, cv2,
                                                       x0, x0, xs1, xs3,
                                                       nullptr, 1.0f);
    // step 2: x2 = 2 * (A @ x1) - x0 (fused Chebyshev epilogue)
    spmm_chunked_kernel<<<spmm_grid, 256, 0, stream>>>(rp1, col1, cv1,
                                                       rp2, col2, cv2,
                                                       xs1, xs3, xs2, xs4,
                                                       x0, 2.0f);

    gemm_kernel<<<NN / 2, 256, 0, stream>>>(ws, W, bias, out);
}